// Round 1
// baseline (49.902 us; speedup 1.0000x reference)
//
#include <hip/hip_runtime.h>
#include <float.h>

// Problem constants (fixed shapes from the reference).
#define BB 8
#define QQ 100
#define CC 19
#define MHH 128
#define MWW 128
#define HWW (MHH * MWW)     // 16384
#define IMG_ 512

// ---------------------------------------------------------------------------
// Kernel 1: per-(b,q) argmax over the first C classes (drop no-object slot).
// 800 threads total.
// ---------------------------------------------------------------------------
__global__ void argmax_kernel(const float* __restrict__ cls,
                              int* __restrict__ pred) {
    int i = blockIdx.x * blockDim.x + threadIdx.x;  // i = b*Q + q
    if (i >= BB * QQ) return;
    const float* p = cls + (size_t)i * (CC + 1);
    float best = p[0];
    int bi = 0;
#pragma unroll
    for (int c = 1; c < CC; ++c) {
        float v = p[c];
        if (v > best) { best = v; bi = c; }  // strict '>' keeps first max (jnp.argmax)
    }
    pred[i] = bi;
}

// ---------------------------------------------------------------------------
// Kernel 2: grouped scatter-max.  One (b,c) plane per blockIdx.x; blockIdx.y
// splits the 16384 pixels into 8 chunks for occupancy.  Queries assigned to
// this class are gathered into LDS once, then each thread max-reduces float4
// pixel groups across those queries.  Unassigned classes write zeros.
// ---------------------------------------------------------------------------
__global__ void segmax_kernel(const float* __restrict__ masks,
                              const int* __restrict__ pred,
                              float* __restrict__ seg) {
    const int bc = blockIdx.x;       // b*C + c
    const int b = bc / CC;
    const int c = bc % CC;

    __shared__ int s_q[QQ];
    __shared__ int s_n;
    if (threadIdx.x == 0) s_n = 0;
    __syncthreads();
    if (threadIdx.x < QQ) {
        if (pred[b * QQ + threadIdx.x] == c) {
            int slot = atomicAdd(&s_n, 1);
            s_q[slot] = threadIdx.x;
        }
    }
    __syncthreads();
    const int nq = s_n;

    const int VEC_PER_PLANE = HWW / 4;                 // 4096 float4
    const int CHUNK = VEC_PER_PLANE / gridDim.y;       // e.g. 512
    const int j0 = blockIdx.y * CHUNK;
    const int j1 = j0 + CHUNK;

    float4* out = (float4*)(seg + (size_t)bc * HWW);

    if (nq == 0) {
        float4 z = make_float4(0.f, 0.f, 0.f, 0.f);
        for (int j = j0 + threadIdx.x; j < j1; j += blockDim.x) out[j] = z;
        return;
    }

    for (int j = j0 + threadIdx.x; j < j1; j += blockDim.x) {
        float4 m = make_float4(-FLT_MAX, -FLT_MAX, -FLT_MAX, -FLT_MAX);
        for (int t = 0; t < nq; ++t) {
            const float4* mp =
                (const float4*)(masks + ((size_t)(b * QQ + s_q[t])) * HWW);
            float4 v = mp[j];
            m.x = fmaxf(m.x, v.x);
            m.y = fmaxf(m.y, v.y);
            m.z = fmaxf(m.z, v.z);
            m.w = fmaxf(m.w, v.w);
        }
        out[j] = m;
    }
}

// ---------------------------------------------------------------------------
// Kernel 3: half-pixel bilinear 4x upsample 128 -> 512.
// Each thread emits one aligned float4 = one full horizontal phase group, so
// the fractional weights are compile-time constants:
//   x = 4k+p, src_x = k + (p-1.5)/4 ->
//     p=0: v[k-1]*0.375 + v[k]*0.625
//     p=1: v[k-1]*0.125 + v[k]*0.875
//     p=2: v[k]*0.875 + v[k+1]*0.125
//     p=3: v[k]*0.625 + v[k+1]*0.375
// Border handling: clamped indices == jax's renormalized triangle kernel for
// a 2-tap filter.
// ---------------------------------------------------------------------------
__global__ void resize_kernel(const float* __restrict__ seg,
                              float* __restrict__ out) {
    const int total = BB * CC * IMG_ * (IMG_ / 4);     // 9,961,472 float4 slots
    int tid = blockIdx.x * blockDim.x + threadIdx.x;
    if (tid >= total) return;

    const int xg = tid & (IMG_ / 4 - 1);   // 0..127  (x group)
    const int y  = (tid >> 7) & (IMG_ - 1);
    const int bc = tid >> 16;              // 512*128 slots per plane

    // vertical sample
    float sy = (y + 0.5f) * 0.25f - 0.5f;
    float fy = sy - floorf(sy);
    int y0 = (int)floorf(sy);
    int y1 = min(y0 + 1, MHH - 1);
    y0 = max(y0, 0);

    const float* r0 = seg + ((size_t)bc * MHH + y0) * MWW;
    const float* r1 = seg + ((size_t)bc * MHH + y1) * MWW;

    const int k  = xg;
    const int km = max(k - 1, 0);
    const int kp = min(k + 1, MWW - 1);

    const float wy1 = fy, wy0 = 1.f - fy;
    const float vm = r0[km] * wy0 + r1[km] * wy1;
    const float v0 = r0[k]  * wy0 + r1[k]  * wy1;
    const float vp = r0[kp] * wy0 + r1[kp] * wy1;

    float4 o;
    o.x = vm * 0.375f + v0 * 0.625f;
    o.y = vm * 0.125f + v0 * 0.875f;
    o.z = v0 * 0.875f + vp * 0.125f;
    o.w = v0 * 0.625f + vp * 0.375f;

    ((float4*)out)[tid] = o;
}

// ---------------------------------------------------------------------------
extern "C" void kernel_launch(void* const* d_in, const int* in_sizes, int n_in,
                              void* d_out, int out_size, void* d_ws, size_t ws_size,
                              hipStream_t stream) {
    const float* cls   = (const float*)d_in[0];  // [B, Q, C+1] f32
    const float* masks = (const float*)d_in[1];  // [B, Q, 128, 128] f32
    float* out = (float*)d_out;                  // [B, C, 512, 512] f32

    // workspace layout: pred[800] ints, then seg_logits[B*C*HW] floats
    int*   pred = (int*)d_ws;
    float* seg  = (float*)((char*)d_ws + 4096);

    // 1) per-query class argmax
    argmax_kernel<<<(BB * QQ + 255) / 256, 256, 0, stream>>>(cls, pred);

    // 2) grouped scatter-max into seg logits
    dim3 g2(BB * CC, 8);
    segmax_kernel<<<g2, 256, 0, stream>>>(masks, pred, seg);

    // 3) bilinear 4x upsample
    const int total = BB * CC * IMG_ * (IMG_ / 4);
    resize_kernel<<<(total + 255) / 256, 256, 0, stream>>>(seg, out);
}

// Round 2
// 37.498 us; speedup vs baseline: 1.3308x; 1.3308x over previous
//
#include <hip/hip_runtime.h>
#include <float.h>

// Problem constants (fixed shapes from the reference).
#define BB 8
#define QQ 100
#define CC 19
#define MHH 128
#define MWW 128
#define IMG_ 512

#define BANDS 8
#define BROWS (MHH / BANDS)      // 16 source rows per band
#define SROWS (BROWS + 2)        // +1 halo row each side = 18
#define OROWS (IMG_ / BANDS)     // 64 output rows per band

// ---------------------------------------------------------------------------
// One fused kernel: argmax -> grouped segment-max (into LDS) -> bilinear 4x
// upsample, per (b,c,band) block.  No intermediate HBM buffer.
//
// Bilinear weights (half-pixel, scale 4) are compile-time constants:
//   out index 4j+p samples src j-1/j (p=0,1) or j/j+1 (p=2,3) with weights
//   p=0: .375/.625   p=1: .125/.875   p=2: .875/.125   p=3: .625/.375
// Border handling via index clamp == jax's renormalized 2-tap triangle kernel
// (validated in round 0, absmax 1.6e-2 within threshold).
// ---------------------------------------------------------------------------
__global__ __launch_bounds__(256)
void fused_kernel(const float* __restrict__ cls,
                  const float* __restrict__ masks,
                  float* __restrict__ out) {
    const int bc   = blockIdx.x;           // b*C + c
    const int band = blockIdx.y;           // 0..BANDS-1
    const int b = bc / CC;
    const int c = bc % CC;
    const int tid = threadIdx.x;

    __shared__ int   s_pred[QQ];
    __shared__ int   s_q[QQ];
    __shared__ int   s_n;
    __shared__ float s_tile[SROWS][MWW];   // 18*128*4 = 9216 B

    if (tid == 0) s_n = 0;
    // --- stage 1: per-query argmax over real classes (cls is 64 KB total,
    //     L2/L3-resident across the 1216 blocks) ---
    if (tid < QQ) {
        const float* p = cls + (size_t)(b * QQ + tid) * (CC + 1);
        float best = p[0];
        int bi = 0;
#pragma unroll
        for (int k = 1; k < CC; ++k) {
            float v = p[k];
            if (v > best) { best = v; bi = k; }   // first-max, matches jnp.argmax
        }
        s_pred[tid] = bi;
    }
    __syncthreads();
    if (tid < QQ && s_pred[tid] == c) {
        int slot = atomicAdd(&s_n, 1);
        s_q[slot] = tid;
    }
    __syncthreads();
    const int nq = s_n;

    // --- stage 2: segment-max the 18 (clamped) source rows into LDS ---
    const int r0 = band * BROWS - 1;       // global row of LDS row 0 (unclamped)
    float4* tile4 = (float4*)&s_tile[0][0];
    const int NSLOT = SROWS * (MWW / 4);   // 576 float4 slots
    for (int s = tid; s < NSLOT; s += 256) {
        const int lr = s >> 5;             // 32 float4 per row
        const int cg = s & 31;
        const int g  = min(max(r0 + lr, 0), MHH - 1);
        float4 m = make_float4(0.f, 0.f, 0.f, 0.f);
        if (nq > 0) {
            m = make_float4(-FLT_MAX, -FLT_MAX, -FLT_MAX, -FLT_MAX);
            for (int t = 0; t < nq; ++t) {
                const float4* mp = (const float4*)(
                    masks + (((size_t)(b * QQ + s_q[t])) * MHH + g) * MWW);
                float4 v = mp[cg];
                m.x = fmaxf(m.x, v.x);
                m.y = fmaxf(m.y, v.y);
                m.z = fmaxf(m.z, v.z);
                m.w = fmaxf(m.w, v.w);
            }
        }
        tile4[s] = m;
    }
    __syncthreads();

    // --- stage 3: bilinear 4x upsample, 4 output rows per item ---
    // items: 16 row-groups (j) x 128 x-groups, each emits 4 aligned float4.
    for (int i = tid; i < (BROWS) * (MWW); i += 256) {   // 16*128 = 2048
        const int jj = i >> 7;             // row group within band (0..15)
        const int xg = i & 127;            // float4 column group (0..127)
        const int km = max(xg - 1, 0);
        const int kp = min(xg + 1, MWW - 1);

        // three source rows: global j-1, j, j+1 -> LDS rows jj, jj+1, jj+2
        const float am = s_tile[jj][km],     a0 = s_tile[jj][xg],     ap = s_tile[jj][kp];
        const float bm = s_tile[jj + 1][km], b0 = s_tile[jj + 1][xg], bp = s_tile[jj + 1][kp];
        const float cm = s_tile[jj + 2][km], c0 = s_tile[jj + 2][xg], cp = s_tile[jj + 2][kp];

        float* orow = out + ((size_t)bc * IMG_ + (size_t)band * OROWS + jj * 4) * IMG_;

        float4 o;
        // p = 0: .375*row(j-1) + .625*row(j)
        {
            const float vm = am * 0.375f + bm * 0.625f;
            const float v0 = a0 * 0.375f + b0 * 0.625f;
            const float vp = ap * 0.375f + bp * 0.625f;
            o.x = vm * 0.375f + v0 * 0.625f;
            o.y = vm * 0.125f + v0 * 0.875f;
            o.z = v0 * 0.875f + vp * 0.125f;
            o.w = v0 * 0.625f + vp * 0.375f;
            ((float4*)orow)[xg] = o;
        }
        // p = 1: .125*row(j-1) + .875*row(j)
        {
            const float vm = am * 0.125f + bm * 0.875f;
            const float v0 = a0 * 0.125f + b0 * 0.875f;
            const float vp = ap * 0.125f + bp * 0.875f;
            o.x = vm * 0.375f + v0 * 0.625f;
            o.y = vm * 0.125f + v0 * 0.875f;
            o.z = v0 * 0.875f + vp * 0.125f;
            o.w = v0 * 0.625f + vp * 0.375f;
            ((float4*)(orow + IMG_))[xg] = o;
        }
        // p = 2: .875*row(j) + .125*row(j+1)
        {
            const float vm = bm * 0.875f + cm * 0.125f;
            const float v0 = b0 * 0.875f + c0 * 0.125f;
            const float vp = bp * 0.875f + cp * 0.125f;
            o.x = vm * 0.375f + v0 * 0.625f;
            o.y = vm * 0.125f + v0 * 0.875f;
            o.z = v0 * 0.875f + vp * 0.125f;
            o.w = v0 * 0.625f + vp * 0.375f;
            ((float4*)(orow + 2 * IMG_))[xg] = o;
        }
        // p = 3: .625*row(j) + .375*row(j+1)
        {
            const float vm = bm * 0.625f + cm * 0.375f;
            const float v0 = b0 * 0.625f + c0 * 0.375f;
            const float vp = bp * 0.625f + cp * 0.375f;
            o.x = vm * 0.375f + v0 * 0.625f;
            o.y = vm * 0.125f + v0 * 0.875f;
            o.z = v0 * 0.875f + vp * 0.125f;
            o.w = v0 * 0.625f + vp * 0.375f;
            ((float4*)(orow + 3 * IMG_))[xg] = o;
        }
    }
}

// ---------------------------------------------------------------------------
extern "C" void kernel_launch(void* const* d_in, const int* in_sizes, int n_in,
                              void* d_out, int out_size, void* d_ws, size_t ws_size,
                              hipStream_t stream) {
    const float* cls   = (const float*)d_in[0];  // [B, Q, C+1] f32
    const float* masks = (const float*)d_in[1];  // [B, Q, 128, 128] f32
    float* out = (float*)d_out;                  // [B, C, 512, 512] f32

    dim3 grid(BB * CC, BANDS);                   // 152 x 8 = 1216 blocks
    fused_kernel<<<grid, 256, 0, stream>>>(cls, masks, out);
}